// Round 3
// baseline (796.561 us; speedup 1.0000x reference)
//
#include <hip/hip_runtime.h>

// PositionEmbeddingEncoder: 1M points, 8 grid levels (g = 2^d), gather 8-float
// rows from per-level tables, concat -> [N, 64] f32.
//
// Layout: 8 threads per point-slot, lane handles one depth; each thread
// processes PTS=4 points (p, p+chunk, p+2*chunk, p+3*chunk) so that 8 gather
// loads are in flight per thread before the first store waits (4x the MLP of
// the 1-point version — the w8 gathers are ~900-cycle HBM misses and were
// latency-exposed).
//
// Cache policy:
//  - w8 (512 MB, ~0 reuse) gathers use non-temporal loads -> don't evict
//    w7 (64 MB, ~55% intra-iteration line reuse) / w6 (8 MB) from L2/L3.
//  - out (256 MB, zero reuse, fully coalesced) uses non-temporal stores.
//
// NOTE: __builtin_nontemporal_* requires clang native vector types, not
// HIP_vector_type — hence the ext_vector_type(4) float alias.

#ifndef PTS
#define PTS 4
#endif

typedef float f32x4 __attribute__((ext_vector_type(4)));

__global__ __launch_bounds__(256) void pe_encode_kernel(
    const float* __restrict__ x,
    const float* __restrict__ w1, const float* __restrict__ w2,
    const float* __restrict__ w3, const float* __restrict__ w4,
    const float* __restrict__ w5, const float* __restrict__ w6,
    const float* __restrict__ w7, const float* __restrict__ w8,
    float* __restrict__ out, int n, int chunk)
{
    const int tid = blockIdx.x * blockDim.x + threadIdx.x;
    const int pb  = tid >> 3;      // base point in [0, chunk)
    const int d   = tid & 7;       // depth-1 in [0,8)
    if (pb >= chunk) return;

    // Per-lane table select (d is per-lane; nested cndmask tree).
    const float* tab = (d & 4) ? ((d & 2) ? ((d & 1) ? w8 : w7)
                                          : ((d & 1) ? w6 : w5))
                               : ((d & 2) ? ((d & 1) ? w4 : w3)
                                          : ((d & 1) ? w2 : w1));

    const int   g   = 2 << d;      // 2^(d+1)
    const float gf  = (float)g;
    const float gm1 = gf - 1.0f;
    const bool  big = (d == 7);    // w8: 512 MB, no reuse -> non-temporal

    f32x4 r0[PTS], r1[PTS];
    int   p[PTS];

    // Phase 1: compute all indices, issue all 2*PTS gather loads.
    #pragma unroll
    for (int j = 0; j < PTS; ++j) {
        p[j] = pb + j * chunk;
        if (p[j] < n) {
            // 8 lanes of a group read the same 12B; L1 broadcast.
            const float px = x[p[j] * 3 + 0];
            const float py = x[p[j] * 3 + 1];
            const float pz = x[p[j] * 3 + 2];

            // scaled = (x + 128) / 256 — power-of-two scale, bit-identical to
            // the reference's division.
            const float sx = (px + 128.0f) * (1.0f / 256.0f);
            const float sy = (py + 128.0f) * (1.0f / 256.0f);
            const float sz = (pz + 128.0f) * (1.0f / 256.0f);

            // clip(floor(s*g), 0, g-1) — same op order as reference (no fma).
            const float cxf = fminf(fmaxf(floorf(sx * gf), 0.0f), gm1);
            const float cyf = fminf(fmaxf(floorf(sy * gf), 0.0f), gm1);
            const float czf = fminf(fmaxf(floorf(sz * gf), 0.0f), gm1);

            // Max flat = 2^24-1 (d=7); element offset flat*8 < 2^27 — int ok.
            const int flat = (int)cxf + g * ((int)cyf + g * (int)czf);

            const f32x4* row = (const f32x4*)(tab + (size_t)flat * 8);
            if (big) {
                r0[j] = __builtin_nontemporal_load(row);
                r1[j] = __builtin_nontemporal_load(row + 1);
            } else {
                r0[j] = row[0];
                r1[j] = row[1];
            }
        }
    }

    // Phase 2: coalesced non-temporal stores. For a fixed j, consecutive tids
    // write contiguous 32B chunks -> 2KB contiguous per wave per j.
    f32x4* outv = (f32x4*)out;
    #pragma unroll
    for (int j = 0; j < PTS; ++j) {
        if (p[j] < n) {
            const size_t o = (size_t)p[j] * 16 + (size_t)(d * 2);
            __builtin_nontemporal_store(r0[j], &outv[o]);
            __builtin_nontemporal_store(r1[j], &outv[o + 1]);
        }
    }
}

extern "C" void kernel_launch(void* const* d_in, const int* in_sizes, int n_in,
                              void* d_out, int out_size, void* d_ws, size_t ws_size,
                              hipStream_t stream) {
    const float* x  = (const float*)d_in[0];
    const float* w1 = (const float*)d_in[1];
    const float* w2 = (const float*)d_in[2];
    const float* w3 = (const float*)d_in[3];
    const float* w4 = (const float*)d_in[4];
    const float* w5 = (const float*)d_in[5];
    const float* w6 = (const float*)d_in[6];
    const float* w7 = (const float*)d_in[7];
    const float* w8 = (const float*)d_in[8];
    float* out = (float*)d_out;

    const int n     = in_sizes[0] / 3;              // 1,000,000 points
    const int chunk = (n + PTS - 1) / PTS;          // points per j-step
    const long long threads = (long long)chunk * 8; // 8 lanes per point
    const int block = 256;
    const int grid  = (int)((threads + block - 1) / block);

    pe_encode_kernel<<<grid, block, 0, stream>>>(x, w1, w2, w3, w4, w5, w6, w7, w8,
                                                 out, n, chunk);
}